// Round 12
// baseline (290.588 us; speedup 1.0000x reference)
//
#include <hip/hip_runtime.h>
#include <cstdint>
#include <cstddef>

#define T_LEN 8192
#define BATCH 64
#define HID   10
#define CH    66
#define EEG   64
#define SM_STRIDE 8384   // 192-entry zero pad + 8192 live, per batch (16B-aligned stride)
#define TSF   2088       // yt row stride (floats): 2080 live (32 warm + 2048) + 8 pad;
                         // 2088*4 B = 16B-aligned rows

// ---------------------------------------------------------------------------
// K12: FUSED front projection + front LIF, v7 = v6 Phase A (verified ~67 us,
// the empirical ceiling for the strided x read after 7 designs) + in-LDS
// Phase B. Rationale: k_front already runs 1 block/CU x 512 thr; keeping y
// in LDS (83 KB tile) removes k_flif's 21 MB write + 31 MB read + one launch
// gap at zero occupancy cost. Phase A: block = (b, t-quarter 2048), ring-4
// c-prefetch, 8 KB bursts, ascending-c FMA chain -> y BIT-IDENTICAL.
// Phase B: 8 waves x one 256-t sub-chunk each, warm 32 from the tile
// (0.25^32 ~ 5e-20), ballot -> smask; round-3-verified structure.
// ---------------------------------------------------------------------------
__global__ __launch_bounds__(512) void k_front_lif(
    const float* __restrict__ x, const float* __restrict__ wf_g,
    const float* __restrict__ bf_g, unsigned short* __restrict__ smask,
    float* __restrict__ out) {
    __shared__ __align__(16) float yt[HID][TSF];   // tile idx k <-> t = t0 - 32 + k
    __shared__ __align__(16) float wf[EEG][12];    // wf[c][h], h-padded to 12
    __shared__ __align__(16) float bf[16];
    int tid = threadIdx.x;
    for (int i = tid; i < EEG * 12; i += 512) {
        int c = i / 12, h = i - 12 * (i / 12);
        wf[c][h] = (h < HID) ? wf_g[h * EEG + c] : 0.f;   // w_front layout (H, C)
    }
    if (tid < HID) bf[tid] = bf_g[tid];

    int bx = blockIdx.x;             // t-quarter 0..3
    int b  = blockIdx.y;             // batch 0..63
    if (bx == 0) {                   // zero the 192-entry smask pad for this batch
        for (int i = tid; i < 96; i += 512)
            ((unsigned*)(smask + (size_t)b * SM_STRIDE))[i] = 0u;
        if (b == 0)                  // fold the out-memset dispatch in here
            for (int i = tid; i < BATCH * 2; i += 512) out[i] = 0.f;
    }
    __syncthreads();

    // ---- Phase A: projection into LDS tile (v6 code; 520 float4 groups
    //      cover [t0-32, t0+2048); ascending-c chain -> bit-identical y) ----
    int t0 = bx * 2048;
    const float* xb = x + ((size_t)b * CH + 1) * T_LEN;   // skip aud channel 0
    for (int g = tid; g < 520; g += 512) {
        int t = t0 - 32 + 4 * g;
        if (t < 0) continue;         // bx==0 head: region never read by Phase B
        const float* xp = xb + t;
        float4 ring[4];              // 4-deep c-prefetch ring (static idx)
#pragma unroll
        for (int j = 0; j < 4; ++j) ring[j] = *(const float4*)(xp + (size_t)j * T_LEN);
        float acc[4][HID];
#pragma unroll
        for (int j = 0; j < 4; ++j)
#pragma unroll
            for (int h = 0; h < HID; ++h) acc[j][h] = bf[h];
#pragma unroll 4
        for (int c = 0; c < EEG; ++c) {
            float4 xv = ring[c & 3];
            if (c + 4 < EEG)         // compile-time under unroll 4
                ring[c & 3] = *(const float4*)(xp + (size_t)(c + 4) * T_LEN);
            float4 w0 = *(const float4*)&wf[c][0];
            float4 w1 = *(const float4*)&wf[c][4];
            float2 w2 = *(const float2*)&wf[c][8];
            float w[HID] = {w0.x, w0.y, w0.z, w0.w, w1.x, w1.y, w1.z, w1.w, w2.x, w2.y};
#pragma unroll
            for (int h = 0; h < HID; ++h) {
                acc[0][h] = fmaf(xv.x, w[h], acc[0][h]);
                acc[1][h] = fmaf(xv.y, w[h], acc[1][h]);
                acc[2][h] = fmaf(xv.z, w[h], acc[2][h]);
                acc[3][h] = fmaf(xv.w, w[h], acc[3][h]);
            }
        }
        int k = 4 * g;
#pragma unroll
        for (int h = 0; h < HID; ++h)
            *(float4*)&yt[h][k] =
                make_float4(acc[0][h], acc[1][h], acc[2][h], acc[3][h]);
    }
    __syncthreads();

    // ---- Phase B: LIF scan, one 256-t sub-chunk per wave, warm 32 ----
    int s    = tid >> 6;             // wave 0..7 -> sub-chunk
    int lane = tid & 63;
    int h    = lane & 15;
    int hh   = h < HID ? h : HID - 1;  // spare lanes duplicate (bits masked)

    int kliv = 32 + 256 * s;                       // first live tile index
    int wl   = (bx == 0 && s == 0) ? 0 : 32;       // warm length
    int ks   = kliv - wl;                          // scan start (mult of 4)
    int nf   = (256 + wl) >> 2;                    // float4 steps (64 or 72)
    const float4* yrow = (const float4*)&yt[hh][0];
    int base = ks >> 2;

    unsigned short* smb = smask + (size_t)b * SM_STRIDE + 192 + t0 + 256 * s;
    float u = 0.f, o = 0.f;
    float4 A = yrow[base], B = yrow[base + 1], C = yrow[base + 2];
    for (int f = 0; f < nf; ++f) {
        int nx = f + 3; if (nx > nf - 1) nx = nf - 1;
        float4 Dv = yrow[base + nx];
        float vv[4] = {A.x, A.y, A.z, A.w};
        int kb = ks + 4 * f;
#pragma unroll
        for (int k2 = 0; k2 < 4; ++k2) {
            u = (o > 0.5f) ? vv[k2] : fmaf(0.25f, u, vv[k2]);   // 0.25*u exact
            bool sp = (u > 0.2f);
            o = sp ? 1.0f : 0.0f;
            unsigned long long bal = __ballot(sp);
            int k = kb + k2;
            if (k >= kliv && h == 0)
                smb[k - kliv] = (unsigned short)(bal & 0x3FFull);
        }
        A = B; B = C; C = Dv;
    }
}

// ---------------------------------------------------------------------------
// K3: LSNN scan + classifier. Direct 1024x22 subset-sum table D (88 KB LDS):
// every rec/X/P lookup is a single ds_read_b32. Unchanged (verified).
// ---------------------------------------------------------------------------
__global__ __launch_bounds__(512) void k_lsnn(
    const unsigned short* __restrict__ smask,
    const float* __restrict__ w_in, const float* __restrict__ w_rec,
    const float* __restrict__ w_cls, const float* __restrict__ b_cls,
    float* __restrict__ out) {
    extern __shared__ float LDSBUF[];
    float* T = LDSBUF;          // [1536]: [hi*768 + m*24 + role]
    float* D = LDSBUF + 1536;   // [1024*22]: full 10-bit subset sums
    int tid = threadIdx.x;
    for (int i = tid; i < 1536; i += 512) {
        int hi = i / 768;
        int rem = i - hi * 768;
        int m = rem / 24, role = rem - m * 24;
        float s = 0.f;
        if (role < 22) {
            const float* wrow = (role < 10) ? (w_in + role * HID)
                              : (role < 12) ? (w_cls + (role - 10) * HID)
                                            : (w_rec + (role - 12) * HID);
#pragma unroll
            for (int j = 0; j < 5; ++j)
                if (m & (1u << j)) s += wrow[hi * 5 + j];
        }
        T[i] = s;
    }
    __syncthreads();
    for (int i = tid; i < 1024 * 22; i += 512) {
        int z = i / 22, role = i - z * 22;
        D[i] = T[(z & 31) * 24 + role] + T[768 + (z >> 5) * 24 + role];
    }
    __syncthreads();

    int lane = tid & 63;
    int q = lane >> 4;                 // unit-in-wave 0..3
    int r = lane & 15;                 // role: 0..9 hidden, 10..11 cls, 12..15 shadow
    int rr = r < 12 ? r : 11;          // X/P table role (shadows duplicate 11)
    int rrec = 12 + (r < HID ? r : 9); // rec table role
    int shq = q * 16;
    int id = blockIdx.x * 32 + (tid >> 4);   // 256*32 = 8192 units, no tail
    int b = id >> 7, chunk = id & 127;

    float bcl = (r == 10 || r == 11) ? b_cls[r - HID] : 0.f;

    const unsigned short* sm = smask + (size_t)b * SM_STRIDE + (size_t)chunk * 64;

    auto xlook = [&](const uint4& mv, float* X) {
        unsigned hw[8] = { mv.x & 0x3FFu, (mv.x >> 16) & 0x3FFu,
                           mv.y & 0x3FFu, (mv.y >> 16) & 0x3FFu,
                           mv.z & 0x3FFu, (mv.z >> 16) & 0x3FFu,
                           mv.w & 0x3FFu, (mv.w >> 16) & 0x3FFu };
#pragma unroll
        for (int u = 0; u < 8; ++u)
            X[u] = D[hw[u] * 22 + rr];
    };

    // 4-deep mask prefetch ring
    uint4 mB = *(const uint4*)(sm + 8);
    uint4 mC = *(const uint4*)(sm + 16);
    uint4 mD = *(const uint4*)(sm + 24);
    float Xc[8], Xn[8], Pc[8], Pn[8];
    { uint4 m0 = *(const uint4*)(sm); xlook(m0, Xc); }
#pragma unroll
    for (int u = 0; u < 8; ++u) { Pc[u] = 0.f; Pn[u] = 0.f; }

    float v = 0.f, cur = 0.f;
    unsigned zmask = 0;
    float uc = 0.f, oc = 0.f, accs = 0.f;

    for (int gr = 0; gr < 32; ++gr) {
        int nb = gr + 4; if (nb > 31) nb = 31;
        uint4 mE = *(const uint4*)(sm + (size_t)nb * 8);
        xlook(mB, Xn);                  // x_in for next group (off-chain)
        unsigned zs[8];
#pragma unroll
        for (int u = 0; u < 8; ++u) {
            float rec = D[zmask * 22 + rrec];
            float ij = (cur + Xc[u]) + rec;
            float vd = v + 0.1f * (ij - v);     // bit-exact form
            cur = ij - 0.2f * ij;               // bit-exact form
            bool zb = vd > 0.2f;                // b_dec == VTH exactly
            unsigned long long bal = __ballot(zb);
            v = zb ? 0.f : vd;
            zmask = (unsigned)(bal >> shq) & 0x3FFu;
            zs[u] = zmask;
        }
        if (gr >= 21) {                        // classifier-input lookups
#pragma unroll
            for (int u = 0; u < 8; ++u)
                Pn[u] = D[zs[u] * 22 + rr];
        }
        if (gr >= 22) {                        // classifier LIF for group gr-1
            bool in = (gr >= 25);              // live groups are 24..31
#pragma unroll
            for (int u = 0; u < 8; ++u) {
                float ci = Pc[u] + bcl;
                uc = (oc > 0.5f) ? ci : fmaf(0.25f, uc, ci);
                oc = (uc > 0.2f) ? 1.f : 0.f;
                if (in) accs += oc;
            }
        }
#pragma unroll
        for (int u = 0; u < 8; ++u) { Xc[u] = Xn[u]; Pc[u] = Pn[u]; }
        mB = mC; mC = mD; mD = mE;
    }
    // epilogue: classifier for group 31 (live)
#pragma unroll
    for (int u = 0; u < 8; ++u) {
        float ci = Pc[u] + bcl;
        uc = (oc > 0.5f) ? ci : fmaf(0.25f, uc, ci);
        oc = (uc > 0.2f) ? 1.f : 0.f;
        accs += oc;
    }
    if (r == 10 || r == 11)
        atomicAdd(&out[b * 2 + (r - 10)], accs * (1.0f / 8192.0f));
}

// ---------------------------------------------------------------------------
extern "C" void kernel_launch(void* const* d_in, const int* in_sizes, int n_in,
                              void* d_out, int out_size, void* d_ws, size_t ws_size,
                              hipStream_t stream) {
    const float* x       = (const float*)d_in[0];
    const float* w_front = (const float*)d_in[1];
    const float* b_front = (const float*)d_in[2];
    const float* w_in    = (const float*)d_in[3];
    const float* w_rec   = (const float*)d_in[4];
    const float* w_cls   = (const float*)d_in[5];
    const float* b_cls   = (const float*)d_in[6];
    float* out = (float*)d_out;

    unsigned short* smask = (unsigned short*)d_ws;   // 64*8384*2 = 1.07 MB (y in LDS)

    k_front_lif<<<dim3(4, BATCH), 512, 0, stream>>>(x, w_front, b_front, smask, out);
    k_lsnn<<<dim3(256), 512, (1536 + 1024 * 22) * sizeof(float), stream>>>(
        smask, w_in, w_rec, w_cls, b_cls, out);
}